// Round 6
// baseline (334.030 us; speedup 1.0000x reference)
//
#include <hip/hip_runtime.h>
#include <stdint.h>

#define EPS_F 1e-7f

typedef float f32x4 __attribute__((ext_vector_type(4)));

union A8 { uint2 u2; long l; };

__device__ __forceinline__ unsigned cvt4(float a, float b, float c, float d) {
  int v = __builtin_amdgcn_cvt_pk_fp8_f32(a, b, 0, false);   // bytes 0,1
  return (unsigned)__builtin_amdgcn_cvt_pk_fp8_f32(c, d, v, true);  // bytes 2,3
}

// ---------------------------------------------------------------------------
// prep: prototypes fp32 (2048x512) -> fp8 e4m3 in MFMA B-fragment order for
// 16x16x32 fp8.  16-B chunk (g,kp2), lane l (q=l>>4, cl=l&15) holds
// col n = 16g + cl;  bytes[0:8) = k [64*kp2 + 8q, +8)         (even K32-step)
//                    bytes[8:16) = k [64*kp2 + 32 + 8q, +8)   (odd  K32-step)
// Also y2[c] (fp32 exact), ry[c] = 1/(1-y2) (clamp never binds: points lie
// inside the radius-0.8 ball -> 1-y2 >= 0.36), minws[r] = +inf (uint-encoded
// float atomicMin buffer), and out = 0.
// ---------------------------------------------------------------------------
__global__ __launch_bounds__(256) void prep_kernel(
    const float* __restrict__ protos, uint8_t* __restrict__ wsB,
    float* __restrict__ y2a, float* __restrict__ rya,
    unsigned* __restrict__ minws, float* __restrict__ out) {
  const int lane = threadIdx.x & 63;
  const int w    = threadIdx.x >> 6;
  const int kp2  = lane >> 2, q = lane & 3;   // writer coords (lanes 0..31)
  const int sl0  = 8 * kp2 + q;               // source lane of even half
  const int sl1  = sl0 + 4;                   // source lane of odd half
#pragma unroll
  for (int i = 0; i < 4; ++i) {
    int c = (blockIdx.x * 4 + w) * 4 + i;
    const float4* p = (const float4*)(protos + (size_t)c * 512 + lane * 8);
    float4 f0 = p[0], f1 = p[1];
    float s = f0.x*f0.x + f0.y*f0.y + f0.z*f0.z + f0.w*f0.w
            + f1.x*f1.x + f1.y*f1.y + f1.z*f1.z + f1.w*f1.w;
#pragma unroll
    for (int off = 32; off > 0; off >>= 1) s += __shfl_xor(s, off, 64);
    if (lane == 0) { y2a[c] = s; rya[c] = 1.f / (1.f - s); }
    unsigned ux = cvt4(f0.x, f0.y, f0.z, f0.w);   // this lane's k [8l, 8l+4)
    unsigned uy = cvt4(f1.x, f1.y, f1.z, f1.w);   // k [8l+4, 8l+8)
    uint4 ch;
    ch.x = __shfl((int)ux, sl0, 64);
    ch.y = __shfl((int)uy, sl0, 64);
    ch.z = __shfl((int)ux, sl1, 64);
    ch.w = __shfl((int)uy, sl1, 64);
    if (lane < 32) {
      int g = c >> 4, cl = c & 15;
      ((uint4*)wsB)[((size_t)g * 8 + kp2) * 64 + q * 16 + cl] = ch;
    }
  }
  // one thread per z-row: init the atomicMin buffer to +inf
  minws[blockIdx.x * 256 + threadIdx.x] = 0x7F800000u;
  if (blockIdx.x == 0 && threadIdx.x == 0) out[0] = 0.f;
}

// ---------------------------------------------------------------------------
// gemm_min: 1024 blocks x 256 thr = 512 row-slabs x 2 col-halves; ALL blocks
// co-resident (4 blocks/CU, 16 waves/CU; LDS 4x33.5 KB, VGPR cap 128).
// Blocks bid and bid+512 share a slab and land on the same XCD (512 % 8 == 0)
// so the second z read hits XCD-L2.
//   - A: 64 rows x 512 K fp8 staged ONCE into 32 KB LDS in A-fragment order;
//     x2 fp32-exact in the staging pass; half 0 also writes x2 to global for
//     the final kernel.  ONE barrier before the main loop.
//   - B: each wave owns 256 cols of its half; register pipeline depth 4 iters
//     (8 b128 in flight) from the L2-resident swizzled 1 MB fp8 image.
//   - per iter (K=64): 4 ds_read_b128 (A) + 2 global b128 (B) + 16 MFMAs.
//   - per-row partial min -> one uint atomicMin per row per block
//     (non-negative floats: uint order == float order).
// ---------------------------------------------------------------------------
__global__ __launch_bounds__(256, 4) void gemm_min_kernel(
    const float* __restrict__ z, const uint8_t* __restrict__ wsB,
    const float* __restrict__ y2a, const float* __restrict__ rya,
    unsigned* __restrict__ minws, float* __restrict__ x2ws) {
  __shared__ uint8_t As[32 * 1024];   // 32 chunks (kp2*4 + rf) x 64 lanes x 16B
  __shared__ float x2s[64];
  __shared__ float minbuf[64][4];

  const int tid  = threadIdx.x;
  const int lane = tid & 63;
  const int w    = tid >> 6;          // wave 0..3
  const int q    = lane >> 4;         // quad 0..3
  const int l15  = lane & 15;
  const int half = blockIdx.x >> 9;          // col half 0/1
  const int slab = blockIdx.x & 511;         // row slab
  const size_t rowbase = (size_t)slab * 64;

  // ---- A staging + fused x2: wave w owns rows w*16 + l15 ----
  {
    const float* rp0 = z + (rowbase + w * 16 + l15) * 512;
    float s = 0.f;
#pragma unroll
    for (int j = 0; j < 8; ++j) {
      const float* rp = rp0 + j * 64 + q * 8;
      float4 a0 = ((const float4*)rp)[0];
      float4 a1 = ((const float4*)rp)[1];
      float4 b0 = ((const float4*)(rp + 32))[0];
      float4 b1 = ((const float4*)(rp + 32))[1];
      s += a0.x*a0.x + a0.y*a0.y + a0.z*a0.z + a0.w*a0.w
         + a1.x*a1.x + a1.y*a1.y + a1.z*a1.z + a1.w*a1.w
         + b0.x*b0.x + b0.y*b0.y + b0.z*b0.z + b0.w*b0.w
         + b1.x*b1.x + b1.y*b1.y + b1.z*b1.z + b1.w*b1.w;
      uint4 ch;
      ch.x = cvt4(a0.x, a0.y, a0.z, a0.w);
      ch.y = cvt4(a1.x, a1.y, a1.z, a1.w);
      ch.z = cvt4(b0.x, b0.y, b0.z, b0.w);
      ch.w = cvt4(b1.x, b1.y, b1.z, b1.w);
      ((uint4*)As)[(j * 4 + w) * 64 + lane] = ch;   // chunk = kp2*4 + rf(=w)
    }
    s += __shfl_xor(s, 16, 64);
    s += __shfl_xor(s, 32, 64);      // sum over the 4 q-lanes of this row
    if (lane < 16) {
      x2s[w * 16 + lane] = s;
      if (half == 0) x2ws[rowbase + w * 16 + lane] = s;
    }
  }
  __syncthreads();  // the ONLY barrier before the final reduction

  const uint4* Ap = (const uint4*)As;
  // wave's B base: col group gbase = half*64 + w*16; chunk = (g*8 + kp2)
  const uint4* Bgw = (const uint4*)wsB + ((size_t)(half * 512 + w * 128)) * 64 + lane;

  // B pipeline: iter i = s*8 + kp2 consumes chunks (s*16 + kp2) and +8.
  uint4 B0w[4], B1w[4];
#pragma unroll
  for (int i = 0; i < 4; ++i) {
    B0w[i] = Bgw[(size_t)i * 64];
    B1w[i] = Bgw[(size_t)(i + 8) * 64];
  }

  float tmin[4][4];
#pragma unroll
  for (int rf = 0; rf < 4; ++rf)
#pragma unroll
    for (int r = 0; r < 4; ++r) tmin[rf][r] = 3.4e38f;

  const float* y2p = y2a + half * 1024 + w * 256 + l15;
  const float* ryp = rya + half * 1024 + w * 256 + l15;

#pragma clang loop unroll(disable)
  for (int s = 0; s < 8; ++s) {
    f32x4 acc[4][2];
#pragma unroll
    for (int rf = 0; rf < 4; ++rf) {
      f32x4 z4 = {0.f, 0.f, 0.f, 0.f};
      acc[rf][0] = z4; acc[rf][1] = z4;
    }
    float y2v0 = y2p[s * 32],      ryv0 = ryp[s * 32];
    float y2v1 = y2p[s * 32 + 16], ryv1 = ryp[s * 32 + 16];

#pragma unroll
    for (int kp2 = 0; kp2 < 8; ++kp2) {
      uint4 bu0 = B0w[kp2 & 3];
      uint4 bu1 = B1w[kp2 & 3];
      {  // prefetch iter i+4 into the just-freed slot (ws pad absorbs tail)
        int ip = s * 8 + kp2 + 4;
        int sp = ip >> 3, kq = ip & 7;
        size_t c0 = (size_t)(sp * 16 + kq) * 64;
        B0w[kp2 & 3] = Bgw[c0];
        B1w[kp2 & 3] = Bgw[c0 + 8 * 64];
      }
      A8 b0lo, b0hi, b1lo, b1hi;
      b0lo.u2 = make_uint2(bu0.x, bu0.y); b0hi.u2 = make_uint2(bu0.z, bu0.w);
      b1lo.u2 = make_uint2(bu1.x, bu1.y); b1hi.u2 = make_uint2(bu1.z, bu1.w);
#pragma unroll
      for (int rf = 0; rf < 4; ++rf) {
        uint4 av = Ap[(kp2 * 4 + rf) * 64 + lane];
        A8 alo, ahi;
        alo.u2 = make_uint2(av.x, av.y);
        ahi.u2 = make_uint2(av.z, av.w);
        acc[rf][0] = __builtin_amdgcn_mfma_f32_16x16x32_fp8_fp8(
            alo.l, b0lo.l, acc[rf][0], 0, 0, 0);
        acc[rf][1] = __builtin_amdgcn_mfma_f32_16x16x32_fp8_fp8(
            alo.l, b1lo.l, acc[rf][1], 0, 0, 0);
        acc[rf][0] = __builtin_amdgcn_mfma_f32_16x16x32_fp8_fp8(
            ahi.l, b0hi.l, acc[rf][0], 0, 0, 0);
        acc[rf][1] = __builtin_amdgcn_mfma_f32_16x16x32_fp8_fp8(
            ahi.l, b1hi.l, acc[rf][1], 0, 0, 0);
      }
    }

    // epilogue: cols c0 = half*1024 + w*256 + s*32 + l15, c1 = c0 + 16
#pragma unroll
    for (int rf = 0; rf < 4; ++rf) {
      float4 x4 = *(const float4*)&x2s[rf * 16 + q * 4];  // rows rf*16+q*4+r
#pragma unroll
      for (int r = 0; r < 4; ++r) {
        float xv = (r == 0) ? x4.x : (r == 1) ? x4.y : (r == 2) ? x4.z : x4.w;
        float u0 = fmaxf(fmaf(-2.f, acc[rf][0][r], xv + y2v0), 0.f) * ryv0;
        float u1 = fmaxf(fmaf(-2.f, acc[rf][1][r], xv + y2v1), 0.f) * ryv1;
        tmin[rf][r] = fminf(tmin[rf][r], fminf(u0, u1));
      }
    }
  }

  // ---- min across the 16 lanes (l15) sharing each row ----
#pragma unroll
  for (int rf = 0; rf < 4; ++rf) {
#pragma unroll
    for (int r = 0; r < 4; ++r) {
      float v = tmin[rf][r];
      v = fminf(v, __shfl_xor(v, 1, 64));
      v = fminf(v, __shfl_xor(v, 2, 64));
      v = fminf(v, __shfl_xor(v, 4, 64));
      v = fminf(v, __shfl_xor(v, 8, 64));
      if (l15 == 0) minbuf[rf * 16 + q * 4 + r][w] = v;
    }
  }
  __syncthreads();

  if (w == 0) {  // lane = row 0..63; u >= 0 so uint order == float order
    float m = fminf(fminf(minbuf[lane][0], minbuf[lane][1]),
                    fminf(minbuf[lane][2], minbuf[lane][3]));
    atomicMin(&minws[rowbase + lane], __float_as_uint(m));
  }
}

// ---------------------------------------------------------------------------
// final: per z-row apply rx = 1/(1-x2), acosh, relu; mean via atomicAdd.
// ---------------------------------------------------------------------------
__global__ __launch_bounds__(256) void final_kernel(
    const unsigned* __restrict__ minws, const float* __restrict__ x2ws,
    const float* __restrict__ marg, float* __restrict__ out) {
  __shared__ float red[4];
  int idx  = blockIdx.x * 256 + threadIdx.x;
  int lane = threadIdx.x & 63;
  int w    = threadIdx.x >> 6;
  float u  = __uint_as_float(minws[idx]);
  float t  = u / (1.f - x2ws[idx]);
  float arg = fmaxf(fmaf(2.f, t, 1.f), 1.f + EPS_F);
  float c   = fmaxf(marg[0] - acoshf(arg), 0.f);
#pragma unroll
  for (int off = 32; off > 0; off >>= 1) c += __shfl_xor(c, off, 64);
  if (lane == 0) red[w] = c;
  __syncthreads();
  if (threadIdx.x == 0)
    atomicAdd(out, (red[0] + red[1] + red[2] + red[3]) * (1.0f / 32768.f));
}

// ---------------------------------------------------------------------------
extern "C" void kernel_launch(void* const* d_in, const int* in_sizes, int n_in,
                              void* d_out, int out_size, void* d_ws, size_t ws_size,
                              hipStream_t stream) {
  const float* z      = (const float*)d_in[0];  // 32768 x 512 fp32
  const float* protos = (const float*)d_in[1];  // 2048 x 512 fp32
  const float* marg   = (const float*)d_in[2];  // scalar
  float* out = (float*)d_out;
  uint8_t* wsB = (uint8_t*)d_ws;                                 // 1 MB image
  // 192 KB pad absorbs the harmless B-pipeline tail over-reads (<= 8 KB).
  char* p = (char*)d_ws + (1 << 20) + 192 * 1024;
  float*    y2a   = (float*)p;            p += 8 * 1024;         // 2048 f32
  float*    rya   = (float*)p;            p += 8 * 1024;         // 2048 f32
  unsigned* minws = (unsigned*)p;         p += 128 * 1024;       // 32768 u32
  float*    x2ws  = (float*)p;                                   // 32768 f32

  prep_kernel<<<128, 256, 0, stream>>>(protos, wsB, y2a, rya, minws, out);
  gemm_min_kernel<<<1024, 256, 0, stream>>>(z, wsB, y2a, rya, minws, x2ws);
  final_kernel<<<128, 256, 0, stream>>>(minws, x2ws, marg, out);
}

// Round 7
// 174.810 us; speedup vs baseline: 1.9108x; 1.9108x over previous
//
#include <hip/hip_runtime.h>
#include <stdint.h>

#define EPS_F 1e-7f

typedef float f32x4 __attribute__((ext_vector_type(4)));

union A8 { uint2 u2; long l; };

__device__ __forceinline__ unsigned cvt4(float a, float b, float c, float d) {
  int v = __builtin_amdgcn_cvt_pk_fp8_f32(a, b, 0, false);   // bytes 0,1
  return (unsigned)__builtin_amdgcn_cvt_pk_fp8_f32(c, d, v, true);  // bytes 2,3
}

// ---------------------------------------------------------------------------
// prep: prototypes fp32 (2048x512) -> fp8 e4m3 in MFMA B-fragment order for
// 16x16x32 fp8.  16-B chunk (g,kp2), lane l (q=l>>4, cl=l&15) holds
// col n = 16g + cl;  bytes[0:8) = k [64*kp2 + 8q, +8)         (even K32-step)
//                    bytes[8:16) = k [64*kp2 + 32 + 8q, +8)   (odd  K32-step)
// Also y2[c] (fp32 exact), ry[c] = 1/(1-y2) (clamp never binds: points lie
// inside the radius-0.8 ball -> 1-y2 >= 0.36), minws[r] = +inf (uint-encoded
// float atomicMin buffer), and out = 0.
// ---------------------------------------------------------------------------
__global__ __launch_bounds__(256) void prep_kernel(
    const float* __restrict__ protos, uint8_t* __restrict__ wsB,
    float* __restrict__ y2a, float* __restrict__ rya,
    unsigned* __restrict__ minws, float* __restrict__ out) {
  const int lane = threadIdx.x & 63;
  const int w    = threadIdx.x >> 6;
  const int kp2  = lane >> 2, q = lane & 3;   // writer coords (lanes 0..31)
  const int sl0  = 8 * kp2 + q;               // source lane of even half
  const int sl1  = sl0 + 4;                   // source lane of odd half
#pragma unroll
  for (int i = 0; i < 4; ++i) {
    int c = (blockIdx.x * 4 + w) * 4 + i;
    const float4* p = (const float4*)(protos + (size_t)c * 512 + lane * 8);
    float4 f0 = p[0], f1 = p[1];
    float s = f0.x*f0.x + f0.y*f0.y + f0.z*f0.z + f0.w*f0.w
            + f1.x*f1.x + f1.y*f1.y + f1.z*f1.z + f1.w*f1.w;
#pragma unroll
    for (int off = 32; off > 0; off >>= 1) s += __shfl_xor(s, off, 64);
    if (lane == 0) { y2a[c] = s; rya[c] = 1.f / (1.f - s); }
    unsigned ux = cvt4(f0.x, f0.y, f0.z, f0.w);   // this lane's k [8l, 8l+4)
    unsigned uy = cvt4(f1.x, f1.y, f1.z, f1.w);   // k [8l+4, 8l+8)
    uint4 ch;
    ch.x = __shfl((int)ux, sl0, 64);
    ch.y = __shfl((int)uy, sl0, 64);
    ch.z = __shfl((int)ux, sl1, 64);
    ch.w = __shfl((int)uy, sl1, 64);
    if (lane < 32) {
      int g = c >> 4, cl = c & 15;
      ((uint4*)wsB)[((size_t)g * 8 + kp2) * 64 + q * 16 + cl] = ch;
    }
  }
  // one thread per z-row: init the atomicMin buffer to +inf
  minws[blockIdx.x * 256 + threadIdx.x] = 0x7F800000u;
  if (blockIdx.x == 0 && threadIdx.x == 0) out[0] = 0.f;
}

// ---------------------------------------------------------------------------
// gemm_min: 1024 blocks x 256 thr = 512 row-slabs x 2 col-halves.
// launch_bounds(256,2): do NOT force 4 waves/EU -- round 6 showed that bound
// squeezes the allocator to 64 VGPRs and spills everything (175 MB scratch
// writes).  At the natural ~128 VGPR / 33.5 KB LDS, hardware occupancy is
// 4 blocks/CU anyway once the grid provides them.
// Blocks bid and bid+512 share a slab and land on the same XCD (512 % 8 == 0)
// so the second z read hits XCD-L2.
//   - A: 64 rows x 512 K fp8 staged ONCE into 32 KB LDS in A-fragment order;
//     x2 fp32-exact in the staging pass; half 0 also writes x2 to global for
//     the final kernel.  ONE barrier before the main loop.
//   - B: each wave owns 256 cols of its half; register pipeline depth 4 iters
//     (8 b128 in flight) from the L2-resident swizzled 1 MB fp8 image.
//   - per iter (K=64): 4 ds_read_b128 (A) + 2 global b128 (B) + 16 MFMAs.
//   - per-row partial min -> one uint atomicMin per row per block
//     (non-negative floats: uint order == float order).
// ---------------------------------------------------------------------------
__global__ __launch_bounds__(256, 2) void gemm_min_kernel(
    const float* __restrict__ z, const uint8_t* __restrict__ wsB,
    const float* __restrict__ y2a, const float* __restrict__ rya,
    unsigned* __restrict__ minws, float* __restrict__ x2ws) {
  __shared__ uint8_t As[32 * 1024];   // 32 chunks (kp2*4 + rf) x 64 lanes x 16B
  __shared__ float x2s[64];
  __shared__ float minbuf[64][4];

  const int tid  = threadIdx.x;
  const int lane = tid & 63;
  const int w    = tid >> 6;          // wave 0..3
  const int q    = lane >> 4;         // quad 0..3
  const int l15  = lane & 15;
  const int half = blockIdx.x >> 9;          // col half 0/1
  const int slab = blockIdx.x & 511;         // row slab
  const size_t rowbase = (size_t)slab * 64;

  // ---- A staging + fused x2: wave w owns rows w*16 + l15 ----
  {
    const float* rp0 = z + (rowbase + w * 16 + l15) * 512;
    float s = 0.f;
#pragma unroll
    for (int j = 0; j < 8; ++j) {
      const float* rp = rp0 + j * 64 + q * 8;
      float4 a0 = ((const float4*)rp)[0];
      float4 a1 = ((const float4*)rp)[1];
      float4 b0 = ((const float4*)(rp + 32))[0];
      float4 b1 = ((const float4*)(rp + 32))[1];
      s += a0.x*a0.x + a0.y*a0.y + a0.z*a0.z + a0.w*a0.w
         + a1.x*a1.x + a1.y*a1.y + a1.z*a1.z + a1.w*a1.w
         + b0.x*b0.x + b0.y*b0.y + b0.z*b0.z + b0.w*b0.w
         + b1.x*b1.x + b1.y*b1.y + b1.z*b1.z + b1.w*b1.w;
      uint4 ch;
      ch.x = cvt4(a0.x, a0.y, a0.z, a0.w);
      ch.y = cvt4(a1.x, a1.y, a1.z, a1.w);
      ch.z = cvt4(b0.x, b0.y, b0.z, b0.w);
      ch.w = cvt4(b1.x, b1.y, b1.z, b1.w);
      ((uint4*)As)[(j * 4 + w) * 64 + lane] = ch;   // chunk = kp2*4 + rf(=w)
    }
    s += __shfl_xor(s, 16, 64);
    s += __shfl_xor(s, 32, 64);      // sum over the 4 q-lanes of this row
    if (lane < 16) {
      x2s[w * 16 + lane] = s;
      if (half == 0) x2ws[rowbase + w * 16 + lane] = s;
    }
  }
  __syncthreads();  // the ONLY barrier before the final reduction

  const uint4* Ap = (const uint4*)As;
  // wave's B base: col group gbase = half*64 + w*16; chunk = (g*8 + kp2)
  const uint4* Bgw = (const uint4*)wsB + ((size_t)(half * 512 + w * 128)) * 64 + lane;

  // B pipeline: iter i = s*8 + kp2 consumes chunks (s*16 + kp2) and +8.
  uint4 B0w[4], B1w[4];
#pragma unroll
  for (int i = 0; i < 4; ++i) {
    B0w[i] = Bgw[(size_t)i * 64];
    B1w[i] = Bgw[(size_t)(i + 8) * 64];
  }

  float tmin[4][4];
#pragma unroll
  for (int rf = 0; rf < 4; ++rf)
#pragma unroll
    for (int r = 0; r < 4; ++r) tmin[rf][r] = 3.4e38f;

  const float* y2p = y2a + half * 1024 + w * 256 + l15;
  const float* ryp = rya + half * 1024 + w * 256 + l15;

#pragma clang loop unroll(disable)
  for (int s = 0; s < 8; ++s) {
    f32x4 acc[4][2];
#pragma unroll
    for (int rf = 0; rf < 4; ++rf) {
      f32x4 z4 = {0.f, 0.f, 0.f, 0.f};
      acc[rf][0] = z4; acc[rf][1] = z4;
    }
    float y2v0 = y2p[s * 32],      ryv0 = ryp[s * 32];
    float y2v1 = y2p[s * 32 + 16], ryv1 = ryp[s * 32 + 16];

#pragma unroll
    for (int kp2 = 0; kp2 < 8; ++kp2) {
      uint4 bu0 = B0w[kp2 & 3];
      uint4 bu1 = B1w[kp2 & 3];
      {  // prefetch iter i+4 into the just-freed slot (ws pad absorbs tail)
        int ip = s * 8 + kp2 + 4;
        int sp = ip >> 3, kq = ip & 7;
        size_t c0 = (size_t)(sp * 16 + kq) * 64;
        B0w[kp2 & 3] = Bgw[c0];
        B1w[kp2 & 3] = Bgw[c0 + 8 * 64];
      }
      A8 b0lo, b0hi, b1lo, b1hi;
      b0lo.u2 = make_uint2(bu0.x, bu0.y); b0hi.u2 = make_uint2(bu0.z, bu0.w);
      b1lo.u2 = make_uint2(bu1.x, bu1.y); b1hi.u2 = make_uint2(bu1.z, bu1.w);
#pragma unroll
      for (int rf = 0; rf < 4; ++rf) {
        uint4 av = Ap[(kp2 * 4 + rf) * 64 + lane];
        A8 alo, ahi;
        alo.u2 = make_uint2(av.x, av.y);
        ahi.u2 = make_uint2(av.z, av.w);
        acc[rf][0] = __builtin_amdgcn_mfma_f32_16x16x32_fp8_fp8(
            alo.l, b0lo.l, acc[rf][0], 0, 0, 0);
        acc[rf][1] = __builtin_amdgcn_mfma_f32_16x16x32_fp8_fp8(
            alo.l, b1lo.l, acc[rf][1], 0, 0, 0);
        acc[rf][0] = __builtin_amdgcn_mfma_f32_16x16x32_fp8_fp8(
            ahi.l, b0hi.l, acc[rf][0], 0, 0, 0);
        acc[rf][1] = __builtin_amdgcn_mfma_f32_16x16x32_fp8_fp8(
            ahi.l, b1hi.l, acc[rf][1], 0, 0, 0);
      }
    }

    // epilogue: cols c0 = half*1024 + w*256 + s*32 + l15, c1 = c0 + 16
#pragma unroll
    for (int rf = 0; rf < 4; ++rf) {
      float4 x4 = *(const float4*)&x2s[rf * 16 + q * 4];  // rows rf*16+q*4+r
#pragma unroll
      for (int r = 0; r < 4; ++r) {
        float xv = (r == 0) ? x4.x : (r == 1) ? x4.y : (r == 2) ? x4.z : x4.w;
        float u0 = fmaxf(fmaf(-2.f, acc[rf][0][r], xv + y2v0), 0.f) * ryv0;
        float u1 = fmaxf(fmaf(-2.f, acc[rf][1][r], xv + y2v1), 0.f) * ryv1;
        tmin[rf][r] = fminf(tmin[rf][r], fminf(u0, u1));
      }
    }
  }

  // ---- min across the 16 lanes (l15) sharing each row ----
#pragma unroll
  for (int rf = 0; rf < 4; ++rf) {
#pragma unroll
    for (int r = 0; r < 4; ++r) {
      float v = tmin[rf][r];
      v = fminf(v, __shfl_xor(v, 1, 64));
      v = fminf(v, __shfl_xor(v, 2, 64));
      v = fminf(v, __shfl_xor(v, 4, 64));
      v = fminf(v, __shfl_xor(v, 8, 64));
      if (l15 == 0) minbuf[rf * 16 + q * 4 + r][w] = v;
    }
  }
  __syncthreads();

  if (w == 0) {  // lane = row 0..63; u >= 0 so uint order == float order
    float m = fminf(fminf(minbuf[lane][0], minbuf[lane][1]),
                    fminf(minbuf[lane][2], minbuf[lane][3]));
    atomicMin(&minws[rowbase + lane], __float_as_uint(m));
  }
}

// ---------------------------------------------------------------------------
// final: per z-row apply rx = 1/(1-x2), acosh, relu; mean via atomicAdd.
// ---------------------------------------------------------------------------
__global__ __launch_bounds__(256) void final_kernel(
    const unsigned* __restrict__ minws, const float* __restrict__ x2ws,
    const float* __restrict__ marg, float* __restrict__ out) {
  __shared__ float red[4];
  int idx  = blockIdx.x * 256 + threadIdx.x;
  int lane = threadIdx.x & 63;
  int w    = threadIdx.x >> 6;
  float u  = __uint_as_float(minws[idx]);
  float t  = u / (1.f - x2ws[idx]);
  float arg = fmaxf(fmaf(2.f, t, 1.f), 1.f + EPS_F);
  float c   = fmaxf(marg[0] - acoshf(arg), 0.f);
#pragma unroll
  for (int off = 32; off > 0; off >>= 1) c += __shfl_xor(c, off, 64);
  if (lane == 0) red[w] = c;
  __syncthreads();
  if (threadIdx.x == 0)
    atomicAdd(out, (red[0] + red[1] + red[2] + red[3]) * (1.0f / 32768.f));
}

// ---------------------------------------------------------------------------
extern "C" void kernel_launch(void* const* d_in, const int* in_sizes, int n_in,
                              void* d_out, int out_size, void* d_ws, size_t ws_size,
                              hipStream_t stream) {
  const float* z      = (const float*)d_in[0];  // 32768 x 512 fp32
  const float* protos = (const float*)d_in[1];  // 2048 x 512 fp32
  const float* marg   = (const float*)d_in[2];  // scalar
  float* out = (float*)d_out;
  uint8_t* wsB = (uint8_t*)d_ws;                                 // 1 MB image
  // 192 KB pad absorbs the harmless B-pipeline tail over-reads (<= 8 KB).
  char* p = (char*)d_ws + (1 << 20) + 192 * 1024;
  float*    y2a   = (float*)p;            p += 8 * 1024;         // 2048 f32
  float*    rya   = (float*)p;            p += 8 * 1024;         // 2048 f32
  unsigned* minws = (unsigned*)p;         p += 128 * 1024;       // 32768 u32
  float*    x2ws  = (float*)p;                                   // 32768 f32

  prep_kernel<<<128, 256, 0, stream>>>(protos, wsB, y2a, rya, minws, out);
  gemm_min_kernel<<<1024, 256, 0, stream>>>(z, wsB, y2a, rya, minws, x2ws);
  final_kernel<<<128, 256, 0, stream>>>(minws, x2ws, marg, out);
}

// Round 8
// 168.767 us; speedup vs baseline: 1.9792x; 1.0358x over previous
//
#include <hip/hip_runtime.h>
#include <stdint.h>

#define EPS_F 1e-7f

typedef float f32x4 __attribute__((ext_vector_type(4)));

union A8 { uint2 u2; long l; };

__device__ __forceinline__ unsigned cvt4(float a, float b, float c, float d) {
  int v = __builtin_amdgcn_cvt_pk_fp8_f32(a, b, 0, false);   // bytes 0,1
  return (unsigned)__builtin_amdgcn_cvt_pk_fp8_f32(c, d, v, true);  // bytes 2,3
}

// ---------------------------------------------------------------------------
// prep: prototypes fp32 (2048x512) -> fp8 e4m3 in MFMA B-fragment order for
// 16x16x32 fp8.  16-B chunk (g,kp2), lane l (q=l>>4, cl=l&15) holds
// col n = 16g + cl;  bytes[0:8) = k [64*kp2 + 8q, +8)         (even K32-step)
//                    bytes[8:16) = k [64*kp2 + 32 + 8q, +8)   (odd  K32-step)
// Also y2[c] (fp32 exact), ry[c] = 1/(1-y2) (clamp never binds: points lie
// inside the radius-0.8 ball -> 1-y2 >= 0.36), and out = 0.
// ---------------------------------------------------------------------------
__global__ __launch_bounds__(256) void prep_kernel(
    const float* __restrict__ protos, uint8_t* __restrict__ wsB,
    float* __restrict__ y2a, float* __restrict__ rya,
    float* __restrict__ out) {
  const int lane = threadIdx.x & 63;
  const int w    = threadIdx.x >> 6;
  const int kp2  = lane >> 2, q = lane & 3;   // writer coords (lanes 0..31)
  const int sl0  = 8 * kp2 + q;               // source lane of even half
  const int sl1  = sl0 + 4;                   // source lane of odd half
#pragma unroll
  for (int i = 0; i < 4; ++i) {
    int c = (blockIdx.x * 4 + w) * 4 + i;
    const float4* p = (const float4*)(protos + (size_t)c * 512 + lane * 8);
    float4 f0 = p[0], f1 = p[1];
    float s = f0.x*f0.x + f0.y*f0.y + f0.z*f0.z + f0.w*f0.w
            + f1.x*f1.x + f1.y*f1.y + f1.z*f1.z + f1.w*f1.w;
#pragma unroll
    for (int off = 32; off > 0; off >>= 1) s += __shfl_xor(s, off, 64);
    if (lane == 0) { y2a[c] = s; rya[c] = 1.f / (1.f - s); }
    unsigned ux = cvt4(f0.x, f0.y, f0.z, f0.w);   // this lane's k [8l, 8l+4)
    unsigned uy = cvt4(f1.x, f1.y, f1.z, f1.w);   // k [8l+4, 8l+8)
    uint4 ch;
    ch.x = __shfl((int)ux, sl0, 64);
    ch.y = __shfl((int)uy, sl0, 64);
    ch.z = __shfl((int)ux, sl1, 64);
    ch.w = __shfl((int)uy, sl1, 64);
    if (lane < 32) {
      int g = c >> 4, cl = c & 15;
      ((uint4*)wsB)[((size_t)g * 8 + kp2) * 64 + q * 16 + cl] = ch;
    }
  }
  if (blockIdx.x == 0 && threadIdx.x == 0) out[0] = 0.f;
}

// ---------------------------------------------------------------------------
// gemm_min: 512 blocks x 512 thr (8 waves) = one 64-row slab per block, all
// 2048 cols in-block (round-5 decomposition — no duplicated staging, z read
// once).  2 blocks/CU x 8 waves = 16 waves/CU = 4 waves/SIMD: doubles the
// wave pool vs round 5 (which sat at 2/SIMD, MfmaUtil 34%) with identical
// per-wave instruction mix.  launch_bounds(512,2) leaves the register
// allocator at its natural ~128 VGPR (round-6 lesson: forcing more waves
// squeezes to 64 VGPR and spills catastrophically).
//   - A: 64 rows x 512 K fp8 staged ONCE into 32 KB LDS in A-fragment order;
//     wave w stages row-frag (w&3), k-half (w>>2); x2 via two fp32 partials
//     in LDS.  ONE barrier before the main loop.
//   - B: wave w owns cols [w*256, +256): 8 strips x 8 kp2; register pipeline
//     depth 4 iters (8 b128 in flight) from the L2-resident swizzled image.
//   - per iter (K=64): 4 ds_read_b128 (A) + 2 global b128 (B) + 16 MFMAs.
//   - epilogue per strip: tmin = min(tmin, max(x2+y2-2dot,0)*ry); 1/(1-x2)
//     folded once per row at the end (monotone); in-block full min ->
//     acosh/relu/mean, one atomicAdd per block.
// ---------------------------------------------------------------------------
__global__ __launch_bounds__(512, 2) void gemm_min_kernel(
    const float* __restrict__ z, const uint8_t* __restrict__ wsB,
    const float* __restrict__ y2a, const float* __restrict__ rya,
    const float* __restrict__ marg, float* __restrict__ out) {
  __shared__ uint8_t As[32 * 1024];   // 32 chunks (kp2*4 + rf) x 64 lanes x 16B
  __shared__ float x2p[2][64];        // per-k-half partial row norms
  __shared__ float minbuf[64][8];

  const int tid  = threadIdx.x;
  const int lane = tid & 63;
  const int w    = tid >> 6;          // wave 0..7
  const int wk   = w >> 2;            // k-half 0/1
  const int wr   = w & 3;             // row-frag 0..3
  const int q    = lane >> 4;         // quad 0..3
  const int l15  = lane & 15;
  const size_t rowbase = (size_t)blockIdx.x * 64;

  // ---- A staging + partial x2: wave w stages rows wr*16+l15, k-half wk ----
  {
    const float* rp0 = z + (rowbase + wr * 16 + l15) * 512 + wk * 256;
    float s = 0.f;
#pragma unroll
    for (int j = 0; j < 4; ++j) {
      const float* rp = rp0 + j * 64 + q * 8;
      float4 a0 = ((const float4*)rp)[0];
      float4 a1 = ((const float4*)rp)[1];
      float4 b0 = ((const float4*)(rp + 32))[0];
      float4 b1 = ((const float4*)(rp + 32))[1];
      s += a0.x*a0.x + a0.y*a0.y + a0.z*a0.z + a0.w*a0.w
         + a1.x*a1.x + a1.y*a1.y + a1.z*a1.z + a1.w*a1.w
         + b0.x*b0.x + b0.y*b0.y + b0.z*b0.z + b0.w*b0.w
         + b1.x*b1.x + b1.y*b1.y + b1.z*b1.z + b1.w*b1.w;
      uint4 ch;
      ch.x = cvt4(a0.x, a0.y, a0.z, a0.w);
      ch.y = cvt4(a1.x, a1.y, a1.z, a1.w);
      ch.z = cvt4(b0.x, b0.y, b0.z, b0.w);
      ch.w = cvt4(b1.x, b1.y, b1.z, b1.w);
      // chunk = kp2*4 + rf, kp2 = wk*4 + j, rf = wr
      ((uint4*)As)[((wk * 4 + j) * 4 + wr) * 64 + lane] = ch;
    }
    s += __shfl_xor(s, 16, 64);
    s += __shfl_xor(s, 32, 64);      // sum over the 4 q-lanes of this row
    if (lane < 16) x2p[wk][wr * 16 + lane] = s;
  }
  __syncthreads();  // the ONLY barrier before the final reduction

  // x2 resident per lane: rows rf*16 + q*4 + r
  float x2r[4][4];
#pragma unroll
  for (int rf = 0; rf < 4; ++rf) {
    float4 xa = *(const float4*)&x2p[0][rf * 16 + q * 4];
    float4 xb = *(const float4*)&x2p[1][rf * 16 + q * 4];
    x2r[rf][0] = xa.x + xb.x; x2r[rf][1] = xa.y + xb.y;
    x2r[rf][2] = xa.z + xb.z; x2r[rf][3] = xa.w + xb.w;
  }

  const uint4* Ap = (const uint4*)As;
  // wave's B base: col groups g = w*16 + s*2 (+1); chunk = g*8 + kp2
  const uint4* Bgw = (const uint4*)wsB + (size_t)(w * 128) * 64 + lane;

  // B pipeline: iter i = s*8 + kp2 consumes chunks (s*16 + kp2) and +8.
  uint4 B0w[4], B1w[4];
#pragma unroll
  for (int i = 0; i < 4; ++i) {
    B0w[i] = Bgw[(size_t)i * 64];
    B1w[i] = Bgw[(size_t)(i + 8) * 64];
  }

  float tmin[4][4];
#pragma unroll
  for (int rf = 0; rf < 4; ++rf)
#pragma unroll
    for (int r = 0; r < 4; ++r) tmin[rf][r] = 3.4e38f;

  const float* y2p = y2a + w * 256 + l15;
  const float* ryp = rya + w * 256 + l15;

#pragma clang loop unroll(disable)
  for (int s = 0; s < 8; ++s) {
    f32x4 acc[4][2];
#pragma unroll
    for (int rf = 0; rf < 4; ++rf) {
      f32x4 z4 = {0.f, 0.f, 0.f, 0.f};
      acc[rf][0] = z4; acc[rf][1] = z4;
    }
    float y2v0 = y2p[s * 32],      ryv0 = ryp[s * 32];
    float y2v1 = y2p[s * 32 + 16], ryv1 = ryp[s * 32 + 16];

#pragma unroll
    for (int kp2 = 0; kp2 < 8; ++kp2) {
      uint4 bu0 = B0w[kp2 & 3];
      uint4 bu1 = B1w[kp2 & 3];
      {  // prefetch iter i+4 into the just-freed slot (ws pad absorbs tail)
        int ip = s * 8 + kp2 + 4;
        int sp = ip >> 3, kq = ip & 7;
        size_t c0 = (size_t)(sp * 16 + kq) * 64;
        B0w[kp2 & 3] = Bgw[c0];
        B1w[kp2 & 3] = Bgw[c0 + 8 * 64];
      }
      A8 b0lo, b0hi, b1lo, b1hi;
      b0lo.u2 = make_uint2(bu0.x, bu0.y); b0hi.u2 = make_uint2(bu0.z, bu0.w);
      b1lo.u2 = make_uint2(bu1.x, bu1.y); b1hi.u2 = make_uint2(bu1.z, bu1.w);
#pragma unroll
      for (int rf = 0; rf < 4; ++rf) {
        uint4 av = Ap[(kp2 * 4 + rf) * 64 + lane];
        A8 alo, ahi;
        alo.u2 = make_uint2(av.x, av.y);
        ahi.u2 = make_uint2(av.z, av.w);
        acc[rf][0] = __builtin_amdgcn_mfma_f32_16x16x32_fp8_fp8(
            alo.l, b0lo.l, acc[rf][0], 0, 0, 0);
        acc[rf][1] = __builtin_amdgcn_mfma_f32_16x16x32_fp8_fp8(
            alo.l, b1lo.l, acc[rf][1], 0, 0, 0);
        acc[rf][0] = __builtin_amdgcn_mfma_f32_16x16x32_fp8_fp8(
            ahi.l, b0hi.l, acc[rf][0], 0, 0, 0);
        acc[rf][1] = __builtin_amdgcn_mfma_f32_16x16x32_fp8_fp8(
            ahi.l, b1hi.l, acc[rf][1], 0, 0, 0);
      }
    }

    // epilogue: cols c0 = w*256 + s*32 + l15, c1 = c0 + 16
#pragma unroll
    for (int rf = 0; rf < 4; ++rf) {
#pragma unroll
      for (int r = 0; r < 4; ++r) {
        float xv = x2r[rf][r];
        float u0 = fmaxf(fmaf(-2.f, acc[rf][0][r], xv + y2v0), 0.f) * ryv0;
        float u1 = fmaxf(fmaf(-2.f, acc[rf][1][r], xv + y2v1), 0.f) * ryv1;
        tmin[rf][r] = fminf(tmin[rf][r], fminf(u0, u1));
      }
    }
  }

  // ---- min across the 16 lanes (l15) sharing each row ----
#pragma unroll
  for (int rf = 0; rf < 4; ++rf) {
#pragma unroll
    for (int r = 0; r < 4; ++r) {
      float v = tmin[rf][r];
      v = fminf(v, __shfl_xor(v, 1, 64));
      v = fminf(v, __shfl_xor(v, 2, 64));
      v = fminf(v, __shfl_xor(v, 4, 64));
      v = fminf(v, __shfl_xor(v, 8, 64));
      if (l15 == 0) minbuf[rf * 16 + q * 4 + r][w] = v;
    }
  }
  __syncthreads();

  if (w == 0) {  // lane = row 0..63
    float m = 3.4e38f;
#pragma unroll
    for (int j = 0; j < 8; ++j) m = fminf(m, minbuf[lane][j]);
    float x2 = x2p[0][lane] + x2p[1][lane];
    float t = m / (1.f - x2);                // fold 1/(1-x2) once per row
    float arg = fmaxf(fmaf(2.f, t, 1.f), 1.f + EPS_F);
    float contrib = fmaxf(marg[0] - acoshf(arg), 0.f);
#pragma unroll
    for (int off = 32; off > 0; off >>= 1) contrib += __shfl_xor(contrib, off, 64);
    if (lane == 0) atomicAdd(out, contrib * (1.0f / 32768.f));
  }
}

// ---------------------------------------------------------------------------
extern "C" void kernel_launch(void* const* d_in, const int* in_sizes, int n_in,
                              void* d_out, int out_size, void* d_ws, size_t ws_size,
                              hipStream_t stream) {
  const float* z      = (const float*)d_in[0];  // 32768 x 512 fp32
  const float* protos = (const float*)d_in[1];  // 2048 x 512 fp32
  const float* marg   = (const float*)d_in[2];  // scalar
  float* out = (float*)d_out;
  uint8_t* wsB = (uint8_t*)d_ws;                                 // 1 MB image
  // 192 KB pad absorbs the harmless B-pipeline tail over-reads (<= 8 KB).
  char* p = (char*)d_ws + (1 << 20) + 192 * 1024;
  float* y2a = (float*)p;                 p += 8 * 1024;         // 2048 f32
  float* rya = (float*)p;                                        // 2048 f32

  prep_kernel<<<128, 256, 0, stream>>>(protos, wsB, y2a, rya, out);
  gemm_min_kernel<<<512, 512, 0, stream>>>(z, wsB, y2a, rya, marg, out);
}

// Round 9
// 166.571 us; speedup vs baseline: 2.0053x; 1.0132x over previous
//
#include <hip/hip_runtime.h>
#include <stdint.h>

#define EPS_F 1e-7f

typedef float f32x16 __attribute__((ext_vector_type(16)));
typedef int   i32x8  __attribute__((ext_vector_type(8)));

union F8 { struct { uint4 lo, hi; } q; i32x8 v; };

__device__ __forceinline__ unsigned cvt4(float a, float b, float c, float d) {
  int v = __builtin_amdgcn_cvt_pk_fp8_f32(a, b, 0, false);   // bytes 0,1
  return (unsigned)__builtin_amdgcn_cvt_pk_fp8_f32(c, d, v, true);  // bytes 2,3
}

#define SCALE1 0x7F7F7F7F  // e8m0 127 = 2^0 in every byte -> scale 1.0

// ---------------------------------------------------------------------------
// Shared fragment convention (A and B use the SAME rule, so any HW k-perm
// cancels in the dot product):  16-B chunk (grp, kp, u), lane l (h=l>>5):
//   row/col = grp*32 + (l&31);  k = kp*64 + u*32 + h*16 + j,  j in [0,16).
// A-frag (32x32x64) = chunks (kp,u=0),(kp,u=1) -> regs v[0:3],v[4:7].
// B identical.  Chunk linear index (B image): ((cg*8 + kp)*2 + u).
// ---------------------------------------------------------------------------

// prep: prototypes fp32 (2048x512) -> fp8 e4m3 B image in the convention
// above; y2[c] (fp32 exact); ry[c] = 1/(1-y2) (clamp never binds: points lie
// inside the radius-0.8 ball -> 1-y2 >= 0.36); out = 0.
// Thread t_global: proto p = t>>4, idx = t&15 -> kgroups {idx, idx+16}
// (16-lane groups read 1 KB of a proto row fully coalesced).
__global__ __launch_bounds__(256) void prep_kernel(
    const float* __restrict__ protos, uint8_t* __restrict__ wsB,
    float* __restrict__ y2a, float* __restrict__ rya,
    float* __restrict__ out) {
  int tg  = blockIdx.x * 256 + threadIdx.x;   // [0, 32768)
  int p   = tg >> 4;
  int idx = tg & 15;
  float s = 0.f;
#pragma unroll
  for (int i = 0; i < 2; ++i) {
    int kg = idx + i * 16;                    // kgroup in [0,32)
    const float4* pp = (const float4*)(protos + (size_t)p * 512 + kg * 16);
    float4 f0 = pp[0], f1 = pp[1], f2 = pp[2], f3 = pp[3];
    s += f0.x*f0.x + f0.y*f0.y + f0.z*f0.z + f0.w*f0.w
       + f1.x*f1.x + f1.y*f1.y + f1.z*f1.z + f1.w*f1.w
       + f2.x*f2.x + f2.y*f2.y + f2.z*f2.z + f2.w*f2.w
       + f3.x*f3.x + f3.y*f3.y + f3.z*f3.z + f3.w*f3.w;
    uint4 ch;
    ch.x = cvt4(f0.x, f0.y, f0.z, f0.w);
    ch.y = cvt4(f1.x, f1.y, f1.z, f1.w);
    ch.z = cvt4(f2.x, f2.y, f2.z, f2.w);
    ch.w = cvt4(f3.x, f3.y, f3.z, f3.w);
    int kp = kg >> 2, w2 = kg & 3, u = w2 >> 1, h = w2 & 1;
    int chunk = ((p >> 5) * 8 + kp) * 2 + u;
    int lane  = h * 32 + (p & 31);
    ((uint4*)wsB)[chunk * 64 + lane] = ch;
  }
  // reduce x2 across the 16 lanes sharing p (lanes 16-aligned in a wave)
  s += __shfl_xor(s, 1, 64);
  s += __shfl_xor(s, 2, 64);
  s += __shfl_xor(s, 4, 64);
  s += __shfl_xor(s, 8, 64);
  if (idx == 0) { y2a[p] = s; rya[p] = 1.f / (1.f - s); }
  if (tg == 0) out[0] = 0.f;
}

// ---------------------------------------------------------------------------
// gemm_min: 512 blocks x 256 thr (4 waves), launch_bounds(256,2) — natural
// ~200 VGPR fit (2 waves/SIMD budget 256; round-6 lesson: never force more).
//   - A: 64 rows x 512 K fp8 staged ONCE into 32 KB LDS (convention above);
//     x2 fp32-exact via per-k-class partials.  Two barriers total.
//   - B: wave w owns cols [w*512,+512) = 8 strips of 64; depth-2 register
//     pipeline (8 chunks in flight) from the L2-resident swizzled image.
//   - mfma_scale_f32_32x32x64_f8f6f4 (fp8/fp8, scales=1.0): 2x the
//     non-scaled fp8 rate; per K=64 iter: 4 MFMAs + 4 ds_read_b128 +
//     4 global b128.  Wave tile 64x64, acc 2x2xf32x16.
//   - epilogue per strip: tmin = min(tmin, max(x2+y2-2dot,0)*ry); 1/(1-x2)
//     folded once per row at the end (monotone); in-block min -> acosh/relu,
//     one atomicAdd per block.
// ---------------------------------------------------------------------------
__global__ __launch_bounds__(256, 2) void gemm_min_kernel(
    const float* __restrict__ z, const uint8_t* __restrict__ wsB,
    const float* __restrict__ y2a, const float* __restrict__ rya,
    const float* __restrict__ marg, float* __restrict__ out) {
  __shared__ uint8_t As[32 * 1024];   // 32 chunks x 64 lanes x 16 B
  __shared__ float x2part[4][64];
  __shared__ float x2s[64];
  __shared__ float minbuf[64][4];

  const int tid  = threadIdx.x;
  const int lane = tid & 63;
  const int w    = tid >> 6;          // wave 0..3
  const int l31  = lane & 31;
  const int h    = lane >> 5;
  const size_t rowbase = (size_t)blockIdx.x * 64;

  // ---- A staging + x2 partials: thread t covers row t&63, k-class t>>6 ----
  {
    const int r  = tid & 63;
    const int wq = tid >> 6;          // k-class: u = wq>>1, hh = wq&1
    const int uu = wq >> 1, hh = wq & 1;
    const float* rp = z + (rowbase + r) * 512;
    float s = 0.f;
#pragma unroll
    for (int g = 0; g < 8; ++g) {
      const float4* pp = (const float4*)(rp + g * 64 + wq * 16);
      float4 f0 = pp[0], f1 = pp[1], f2 = pp[2], f3 = pp[3];
      s += f0.x*f0.x + f0.y*f0.y + f0.z*f0.z + f0.w*f0.w
         + f1.x*f1.x + f1.y*f1.y + f1.z*f1.z + f1.w*f1.w
         + f2.x*f2.x + f2.y*f2.y + f2.z*f2.z + f2.w*f2.w
         + f3.x*f3.x + f3.y*f3.y + f3.z*f3.z + f3.w*f3.w;
      uint4 ch;
      ch.x = cvt4(f0.x, f0.y, f0.z, f0.w);
      ch.y = cvt4(f1.x, f1.y, f1.z, f1.w);
      ch.z = cvt4(f2.x, f2.y, f2.z, f2.w);
      ch.w = cvt4(f3.x, f3.y, f3.z, f3.w);
      ((uint4*)As)[(g * 4 + uu * 2 + (r >> 5)) * 64 + (hh * 32 + (r & 31))] = ch;
    }
    x2part[wq][r] = s;
  }
  __syncthreads();
  if (tid < 64)
    x2s[tid] = x2part[0][tid] + x2part[1][tid] + x2part[2][tid] + x2part[3][tid];
  __syncthreads();

  const uint4* Ap = (const uint4*)As;
  const uint4* Bu = (const uint4*)wsB;

  // ---- B pipeline: prime iters 0,1 of strip 0 (sp=0, kq=i) ----
  uint4 Bpf[2][4];
#pragma unroll
  for (int i = 0; i < 2; ++i) {
    const uint4* pb = Bu + (size_t)(((w * 16) * 8 + i) * 2) * 64 + lane;
    Bpf[i][0] = pb[0];        // cg0, u0
    Bpf[i][1] = pb[64];       // cg0, u1
    Bpf[i][2] = pb[16 * 64];  // cg1, u0
    Bpf[i][3] = pb[17 * 64];  // cg1, u1
  }

  float tmin[2][16];
#pragma unroll
  for (int rf = 0; rf < 2; ++rf)
#pragma unroll
    for (int r = 0; r < 16; ++r) tmin[rf][r] = 3.4e38f;

  const float* y2p = y2a + w * 512 + l31;
  const float* ryp = rya + w * 512 + l31;

#pragma clang loop unroll(disable)
  for (int s = 0; s < 8; ++s) {
    f32x16 acc[2][2];
#pragma unroll
    for (int rf = 0; rf < 2; ++rf)
#pragma unroll
      for (int cf = 0; cf < 2; ++cf)
#pragma unroll
        for (int r = 0; r < 16; ++r) acc[rf][cf][r] = 0.f;

#pragma unroll
    for (int kp = 0; kp < 8; ++kp) {
      const int sl = kp & 1;
      F8 bf0, bf1;
      bf0.q.lo = Bpf[sl][0]; bf0.q.hi = Bpf[sl][1];
      bf1.q.lo = Bpf[sl][2]; bf1.q.hi = Bpf[sl][3];
      {  // prefetch iter idx+2 into the just-freed slot (pad absorbs tail)
        int ip = s * 8 + kp + 2;
        int sp = ip >> 3, kq = ip & 7;
        const uint4* pb =
            Bu + (size_t)(((w * 16 + sp * 2) * 8 + kq) * 2) * 64 + lane;
        Bpf[sl][0] = pb[0];
        Bpf[sl][1] = pb[64];
        Bpf[sl][2] = pb[16 * 64];
        Bpf[sl][3] = pb[17 * 64];
      }
      F8 a0, a1;
      a0.q.lo = Ap[(kp * 4 + 0) * 64 + lane];  // rf0 u0
      a0.q.hi = Ap[(kp * 4 + 2) * 64 + lane];  // rf0 u1
      a1.q.lo = Ap[(kp * 4 + 1) * 64 + lane];  // rf1 u0
      a1.q.hi = Ap[(kp * 4 + 3) * 64 + lane];  // rf1 u1
      acc[0][0] = __builtin_amdgcn_mfma_scale_f32_32x32x64_f8f6f4(
          a0.v, bf0.v, acc[0][0], 0, 0, 0, SCALE1, 0, SCALE1);
      acc[0][1] = __builtin_amdgcn_mfma_scale_f32_32x32x64_f8f6f4(
          a0.v, bf1.v, acc[0][1], 0, 0, 0, SCALE1, 0, SCALE1);
      acc[1][0] = __builtin_amdgcn_mfma_scale_f32_32x32x64_f8f6f4(
          a1.v, bf0.v, acc[1][0], 0, 0, 0, SCALE1, 0, SCALE1);
      acc[1][1] = __builtin_amdgcn_mfma_scale_f32_32x32x64_f8f6f4(
          a1.v, bf1.v, acc[1][1], 0, 0, 0, SCALE1, 0, SCALE1);
    }

    // epilogue: cols c0 = w*512 + s*64 + l31, c1 = c0 + 32
    float y2v0 = y2p[s * 64],      ryv0 = ryp[s * 64];
    float y2v1 = y2p[s * 64 + 32], ryv1 = ryp[s * 64 + 32];
#pragma unroll
    for (int rf = 0; rf < 2; ++rf) {
#pragma unroll
      for (int r = 0; r < 16; ++r) {
        // C/D 32x32: row = rf*32 + (r&3) + 8*(r>>2) + 4*h  [m74/m101]
        float xv = x2s[rf * 32 + (r & 3) + 8 * (r >> 2) + 4 * h];
        float u0 = fmaxf(fmaf(-2.f, acc[rf][0][r], xv + y2v0), 0.f) * ryv0;
        float u1 = fmaxf(fmaf(-2.f, acc[rf][1][r], xv + y2v1), 0.f) * ryv1;
        tmin[rf][r] = fminf(tmin[rf][r], fminf(u0, u1));
      }
    }
  }

  // ---- min across the 32 lanes sharing each row (xor stays in-half) ----
#pragma unroll
  for (int rf = 0; rf < 2; ++rf) {
#pragma unroll
    for (int r = 0; r < 16; ++r) {
      float v = tmin[rf][r];
      v = fminf(v, __shfl_xor(v, 1, 64));
      v = fminf(v, __shfl_xor(v, 2, 64));
      v = fminf(v, __shfl_xor(v, 4, 64));
      v = fminf(v, __shfl_xor(v, 8, 64));
      v = fminf(v, __shfl_xor(v, 16, 64));
      if (l31 == 0)
        minbuf[rf * 32 + (r & 3) + 8 * (r >> 2) + 4 * h][w] = v;
    }
  }
  __syncthreads();

  if (w == 0) {  // lane = row 0..63
    float m = fminf(fminf(minbuf[lane][0], minbuf[lane][1]),
                    fminf(minbuf[lane][2], minbuf[lane][3]));
    float t = m / (1.f - x2s[lane]);         // fold 1/(1-x2) once per row
    float arg = fmaxf(fmaf(2.f, t, 1.f), 1.f + EPS_F);
    float contrib = fmaxf(marg[0] - acoshf(arg), 0.f);
#pragma unroll
    for (int off = 32; off > 0; off >>= 1) contrib += __shfl_xor(contrib, off, 64);
    if (lane == 0) atomicAdd(out, contrib * (1.0f / 32768.f));
  }
}

// ---------------------------------------------------------------------------
extern "C" void kernel_launch(void* const* d_in, const int* in_sizes, int n_in,
                              void* d_out, int out_size, void* d_ws, size_t ws_size,
                              hipStream_t stream) {
  const float* z      = (const float*)d_in[0];  // 32768 x 512 fp32
  const float* protos = (const float*)d_in[1];  // 2048 x 512 fp32
  const float* marg   = (const float*)d_in[2];  // scalar
  float* out = (float*)d_out;
  uint8_t* wsB = (uint8_t*)d_ws;                                 // 1 MB image
  // 192 KB pad absorbs the harmless B-pipeline tail over-reads (<= 90 KB).
  char* p = (char*)d_ws + (1 << 20) + 192 * 1024;
  float* y2a = (float*)p;                 p += 8 * 1024;         // 2048 f32
  float* rya = (float*)p;                                        // 2048 f32

  prep_kernel<<<128, 256, 0, stream>>>(protos, wsB, y2a, rya, out);
  gemm_min_kernel<<<512, 256, 0, stream>>>(z, wsB, y2a, rya, marg, out);
}